// Round 3
// baseline (4219.185 us; speedup 1.0000x reference)
//
#include <hip/hip_runtime.h>
#include <hip/hip_bf16.h>

// Problem constants (from reference)
#define NA 35
#define NM 18
#define NN 53          // NA+NM
#define TT 48
#define HH 32
// output: h_aqi [1024,35,32] then h_meo [1024,18,32]
#define OUT_MEO_BASE (1024*35*32)

typedef unsigned short u16;

__device__ __forceinline__ float bf(u16 u){ return __uint_as_float(((unsigned)u)<<16); }
__device__ __forceinline__ float dot4(float4 a, float4 b){
  return a.x*b.x + a.y*b.y + a.z*b.z + a.w*b.w;
}

struct Params {
  const void *X_aqi, *X_meo, *ctx, *adj, *adjn;
  const void *emb0,*emb1,*emb2,*emb3,*emb4,*emb5,*emb6,*emb7,*emb8;
  const void *Wxa,*Wxm,*Wua,*Wum;
  const void *a0,*a1,*a2,*a3;   // a_aa, a_am, a_ma, a_mm
  const void *wih_a,*whh_a,*bih_a,*bhh_a,*wih_m,*whh_m,*bih_m,*bhh_m;
  const int *Xae,*Xme;
  void* out;
};

// dtype-agnostic float load: fp32 buffer or bf16 buffer, chosen at runtime.
__device__ __forceinline__ float ldf(const void* p, int i, bool isbf){
  return isbf ? bf(((const u16*)p)[i]) : ((const float*)p)[i];
}

// ~122 KB static LDS (gfx950 allows 160 KB/workgroup) -> 1 block/CU
// Every float4-accessed array is 16B-aligned (ds_read_b128 requirement).
struct __align__(16) Smem {
  alignas(16) float w[4][96*36];   // wih_a, whh_a, wih_m, whh_m ; row stride 36 floats = 144 B
  alignas(16) float gb[4][96];     // bih_a, bhh_a, bih_m, bhh_m
  alignas(16) float Wxa[6*32], Wxm[4*32], Wua[14*32], Wum[14*32];   // [k][32]
  alignas(16) float aAll[4][188];  // a_aa/a_am/a_ma/a_mm, 185 used
  alignas(16) float embA[304];     // all 9 embedding tables concatenated (300 used)
  alignas(16) float ctxS[NN][2], ctxD[NN][2];   // context part of src/dst logits (batch-invariant)
  alignas(16) float biasE[NN*56];  // adj_norm*a[184] (or -1e12 where masked)
  alignas(16) float xin[NN*16];    // per-step raw+embedded inputs, 14 used per node
  alignas(16) float featW[NN*32];  // learned part of attention features
  alignas(16) float attri[NN*32];  // aggregation values
  alignas(16) float srcv[NN*2], dstv[NN*2];
  alignas(16) float p[NN*56];      // attention (unnormalized exp)
  alignas(16) float inv[56];       // 1/rowsum (53 used)
  alignas(16) float gx[NN*32];     // GAT output = GRU input  (float4-read)
  alignas(16) float h[NN*32];      // GRU hidden state        (float4-read)
};

__global__ __launch_bounds__(256, 1)
void chgat_gru_kernel(Params p){
  __shared__ Smem sm;
  const int tid = threadIdx.x;
  const int b = blockIdx.x;
  const int d = tid & 31;

  // ---------------- stage 0: runtime dtype detection ----------------
  // adj is exactly {0.0f, 1.0f}. fp32 buffer: every u32 word is 0x00000000 or
  // 0x3F800000. bf16 buffer: words are bf16 pairs; elem0 != 0 (prob 0.7/word)
  // gives a word outside that set. 32 words -> P(miss) = 0.3^32 ~ 1e-17.
  bool isbf = false;
  {
    const unsigned* aw = (const unsigned*)p.adj;
    for (int i=0;i<32;++i){
      unsigned w = aw[i];
      if (w != 0u && w != 0x3F800000u) isbf = true;
    }
  }

  // ---------------- stage 1: stage weights into LDS ----------------
  for (int idx=tid; idx<3072; idx+=256) sm.w[0][(idx>>5)*36+(idx&31)] = ldf(p.wih_a, idx, isbf);
  for (int idx=tid; idx<3072; idx+=256) sm.w[1][(idx>>5)*36+(idx&31)] = ldf(p.whh_a, idx, isbf);
  for (int idx=tid; idx<3072; idx+=256) sm.w[2][(idx>>5)*36+(idx&31)] = ldf(p.wih_m, idx, isbf);
  for (int idx=tid; idx<3072; idx+=256) sm.w[3][(idx>>5)*36+(idx&31)] = ldf(p.whh_m, idx, isbf);
  if (tid < 96){
    sm.gb[0][tid]=ldf(p.bih_a,tid,isbf); sm.gb[1][tid]=ldf(p.bhh_a,tid,isbf);
    sm.gb[2][tid]=ldf(p.bih_m,tid,isbf); sm.gb[3][tid]=ldf(p.bhh_m,tid,isbf);
  }
  if (tid < 192) sm.Wxa[tid] = ldf(p.Wxa, tid, isbf);
  if (tid < 128) sm.Wxm[tid] = ldf(p.Wxm, tid, isbf);
  for (int idx=tid; idx<448; idx+=256) sm.Wua[idx] = ldf(p.Wua, idx, isbf);
  for (int idx=tid; idx<448; idx+=256) sm.Wum[idx] = ldf(p.Wum, idx, isbf);
  for (int idx=tid; idx<185; idx+=256) sm.aAll[0][idx] = ldf(p.a0, idx, isbf);
  for (int idx=tid; idx<185; idx+=256) sm.aAll[1][idx] = ldf(p.a1, idx, isbf);
  for (int idx=tid; idx<185; idx+=256) sm.aAll[2][idx] = ldf(p.a2, idx, isbf);
  for (int idx=tid; idx<185; idx+=256) sm.aAll[3][idx] = ldf(p.a3, idx, isbf);
  // embeddings: offsets {0,70,96,110,158,176,212,238,252}, total 300
  if (tid < 70)  sm.embA[tid]        = ldf(p.emb0, tid, isbf);
  if (tid < 26)  sm.embA[70+tid]     = ldf(p.emb1, tid, isbf);
  if (tid < 14)  sm.embA[96+tid]     = ldf(p.emb2, tid, isbf);
  if (tid < 48)  sm.embA[110+tid]    = ldf(p.emb3, tid, isbf);
  if (tid < 18)  sm.embA[158+tid]    = ldf(p.emb4, tid, isbf);
  if (tid < 36)  sm.embA[176+tid]    = ldf(p.emb5, tid, isbf);
  if (tid < 26)  sm.embA[212+tid]    = ldf(p.emb6, tid, isbf);
  if (tid < 14)  sm.embA[238+tid]    = ldf(p.emb7, tid, isbf);
  if (tid < 48)  sm.embA[252+tid]    = ldf(p.emb8, tid, isbf);
  for (int idx=tid; idx<NN*32; idx+=256) sm.h[idx] = 0.f;
  __syncthreads();

  // ---------------- stage 2: batch-invariant attention constants ----------------
  if (tid < 212){
    int i = tid>>2, v = tid&3, it = (i<NA)?0:1;
    float s = 0.f;
    if (v < 2){
      const float* ac = &sm.aAll[it*2+v][32];       // a_sel[32..91] dotted with context
      for (int c=0;c<60;++c) s += ldf(p.ctx, i*60+c, isbf)*ac[c];
      sm.ctxS[i][v] = s;
    } else {
      const float* ac = &sm.aAll[(v-2)*2+it][124];  // a_sel[124..183]
      for (int c=0;c<60;++c) s += ldf(p.ctx, i*60+c, isbf)*ac[c];
      sm.ctxD[i][v-2] = s;
    }
  }
  for (int idx=tid; idx<NN*NN; idx+=256){
    int i = idx/NN, j = idx - i*NN;
    int sel = ((i<NA)?0:2) + ((j<NA)?0:1);
    float ad = ldf(p.adj, idx, isbf);
    sm.biasE[i*56+j] = (ad > 0.f) ? ldf(p.adjn, idx, isbf)*sm.aAll[sel][184] : -1e12f;
  }
  __syncthreads();

  // ---------------- prefetch t=0 inputs into registers ----------------
  // slot layout: 282 raw float values (aqi 210 + meo 72) then 230 int indices.
  float rv1 = 0.f, rv2r = 0.f; int rv2i = 0;
  {
    int bt = b*TT + 0;
    rv1 = (tid < 210) ? ldf(p.X_aqi, bt*210 + tid, isbf) : ldf(p.X_meo, bt*72 + tid - 210, isbf);
    if (tid < 26) rv2r = ldf(p.X_meo, bt*72 + tid + 46, isbf);
    else { int u = tid - 26; rv2i = (u < 140) ? p.Xae[bt*140 + u] : p.Xme[bt*90 + u - 140]; }
  }

  for (int t=0; t<TT; ++t){
    // ---- ph0: consume prefetched inputs into xin (raw + embedding lookups) ----
    if (tid < 210) sm.xin[(tid/6)*16 + tid%6] = rv1;
    else { int q = tid-210; sm.xin[(NA + (q>>2))*16 + (q&3)] = rv1; }
    if (tid < 26){ int q = tid + 46; sm.xin[(NA + (q>>2))*16 + (q&3)] = rv2r; }
    else {
      int u = tid - 26;
      if (u < 140){
        int n = u>>2, e = u&3;
        int off = (e==0)?0:(e==1)?70:(e==2)?96:110;
        sm.xin[n*16 + 6 + 2*e]     = sm.embA[off + rv2i*2];
        sm.xin[n*16 + 6 + 2*e + 1] = sm.embA[off + rv2i*2 + 1];
      } else {
        int q = u - 140;
        int n = NA + q/5, e = q%5;
        int off = (e==0)?158:(e==1)?176:(e==2)?212:(e==3)?238:252;
        sm.xin[n*16 + 4 + 2*e]     = sm.embA[off + rv2i*2];
        sm.xin[n*16 + 4 + 2*e + 1] = sm.embA[off + rv2i*2 + 1];
      }
    }
    // ---- prefetch t+1 (latency hidden behind this step's compute) ----
    {
      int tn = (t < TT-1) ? t+1 : t;
      int bt = b*TT + tn;
      rv1 = (tid < 210) ? ldf(p.X_aqi, bt*210 + tid, isbf) : ldf(p.X_meo, bt*72 + tid - 210, isbf);
      if (tid < 26) rv2r = ldf(p.X_meo, bt*72 + tid + 46, isbf);
      else { int u = tid - 26; rv2i = (u < 140) ? p.Xae[bt*140 + u] : p.Xme[bt*90 + u - 140]; }
    }
    __syncthreads();   // xin ready

    // ---- ph1: attri = x@Wx, featW = xin@Wu ----
    {
      int ng8 = tid>>5;
      #pragma unroll
      for (int m=0;m<7;++m){
        int n = ng8 + (m<<3);
        if (n >= NN) break;
        const bool isA = (n < NA);
        const float* Wu = isA ? sm.Wua : sm.Wum;
        const float* Wx = isA ? sm.Wxa : sm.Wxm;
        const float* x = &sm.xin[n*16];
        float fw = 0.f, at = 0.f;
        #pragma unroll
        for (int k=0;k<14;++k) fw += x[k]*Wu[k*32+d];
        if (isA){
          #pragma unroll
          for (int k=0;k<6;++k) at += x[k]*Wx[k*32+d];
        } else {
          #pragma unroll
          for (int k=0;k<4;++k) at += x[k]*Wx[k*32+d];
        }
        sm.featW[n*32+d] = fw;
        sm.attri[n*32+d] = at;
      }
    }
    __syncthreads();

    // ---- ph2: src/dst logit halves (learned 32 dims + precomputed ctx part) ----
    if (tid < 212){
      int i = tid>>2, v = tid&3, it = (i<NA)?0:1;
      const float* fv = &sm.featW[i*32];
      float s; const float* ac;
      if (v < 2){ s = sm.ctxS[i][v];   ac = &sm.aAll[it*2+v][0]; }
      else      { s = sm.ctxD[i][v-2]; ac = &sm.aAll[(v-2)*2+it][92]; }
      #pragma unroll
      for (int k=0;k<32;++k) s += fv[k]*ac[k];
      if (v < 2) sm.srcv[i*2+v] = s; else sm.dstv[i*2+(v-2)] = s;
    }
    __syncthreads();

    // ---- ph3: e = leaky(src+dst+bias), masked softmax over j (4 lanes/row) ----
    if (tid < 212){
      int i = tid>>2, l = tid&3, it = (i<NA)?0:1;
      float s0 = sm.srcv[i*2+0], s1 = sm.srcv[i*2+1];
      float mx = -3.0e38f;
      for (int j=l; j<NN; j+=4){
        float e = ((j<NA)? s0 : s1) + sm.dstv[j*2+it] + sm.biasE[i*56+j];
        e = (e >= 0.f) ? e : 0.2f*e;
        sm.p[i*56+j] = e;
        mx = fmaxf(mx, e);
      }
      mx = fmaxf(mx, __shfl_xor(mx,1,64));
      mx = fmaxf(mx, __shfl_xor(mx,2,64));
      float sum = 0.f;
      for (int j=l; j<NN; j+=4){
        float pe = __expf(sm.p[i*56+j] - mx);
        sm.p[i*56+j] = pe;
        sum += pe;
      }
      sum += __shfl_xor(sum,1,64);
      sum += __shfl_xor(sum,2,64);
      if (l == 0) sm.inv[i] = 1.0f/sum;
    }
    __syncthreads();

    // ---- ph4: gx = softmax(att) @ attri ----
    {
      int ig = tid>>5;
      float a0=0,a1=0,a2=0,a3=0,a4=0,a5=0,a6=0;
      for (int j=0;j<NN;++j){
        float av = sm.attri[j*32+d];
        const float* pc = &sm.p[j];
        a0 += pc[(ig    )*56]*av;
        a1 += pc[(ig+ 8)*56]*av;
        a2 += pc[(ig+16)*56]*av;
        a3 += pc[(ig+24)*56]*av;
        a4 += pc[(ig+32)*56]*av;
        a5 += pc[(ig+40)*56]*av;
        if (ig+48 < NN) a6 += pc[(ig+48)*56]*av;
      }
      sm.gx[(ig    )*32+d] = a0*sm.inv[ig];
      sm.gx[(ig+ 8)*32+d] = a1*sm.inv[ig+8];
      sm.gx[(ig+16)*32+d] = a2*sm.inv[ig+16];
      sm.gx[(ig+24)*32+d] = a3*sm.inv[ig+24];
      sm.gx[(ig+32)*32+d] = a4*sm.inv[ig+32];
      sm.gx[(ig+40)*32+d] = a5*sm.inv[ig+40];
      if (ig+48 < NN) sm.gx[(ig+48)*32+d] = a6*sm.inv[ig+48];
    }
    __syncthreads();

    // ---- ph5: GRU per node-type. Thread = (d, ks half of k, wave = node group). ----
    {
      const int ng = tid>>6;          // wave index, owns nodes n ≡ ng (mod 4)
      const int ks = (tid>>5)&1;      // k-split half
      const int k0 = ks*16;
      const bool last = (t == TT-1);
      auto gru = [&](const float* __restrict__ wih, const float* __restrict__ whh,
                     const float* __restrict__ bi,  const float* __restrict__ bh,
                     int nbase, int cnt, long long obase){
        float rs[9], zs[9], in_[9], hn[9];
        #pragma unroll
        for (int m=0;m<9;++m){ rs[m]=0.f; zs[m]=0.f; in_[m]=0.f; hn[m]=0.f; }
        #pragma unroll
        for (int kq=0;kq<4;++kq){
          int k = k0 + kq*4;
          float4 wir = *(const float4*)&wih[(d   )*36+k];
          float4 wiz = *(const float4*)&wih[(32+d)*36+k];
          float4 win = *(const float4*)&wih[(64+d)*36+k];
          float4 whr = *(const float4*)&whh[(d   )*36+k];
          float4 whz = *(const float4*)&whh[(32+d)*36+k];
          float4 whn = *(const float4*)&whh[(64+d)*36+k];
          #pragma unroll
          for (int m=0;m<9;++m){
            if (m >= cnt) break;
            int n = nbase + ng + (m<<2);
            float4 x4 = *(const float4*)&sm.gx[n*32+k];
            float4 h4 = *(const float4*)&sm.h[n*32+k];
            rs[m]  += dot4(x4,wir) + dot4(h4,whr);
            zs[m]  += dot4(x4,wiz) + dot4(h4,whz);
            in_[m] += dot4(x4,win);
            hn[m]  += dot4(h4,whn);
          }
        }
        #pragma unroll
        for (int m=0;m<9;++m){
          if (m >= cnt) break;
          rs[m]  += __shfl_xor(rs[m],32,64);
          zs[m]  += __shfl_xor(zs[m],32,64);
          in_[m] += __shfl_xor(in_[m],32,64);
          hn[m]  += __shfl_xor(hn[m],32,64);
        }
        if (ks == 0){
          float br = bi[d]+bh[d], bz = bi[32+d]+bh[32+d];
          float bin = bi[64+d], bhn = bh[64+d];
          #pragma unroll
          for (int m=0;m<9;++m){
            if (m >= cnt) break;
            int n = nbase + ng + (m<<2);
            float r = 1.f/(1.f+__expf(-(rs[m]+br)));
            float z = 1.f/(1.f+__expf(-(zs[m]+bz)));
            float pre = (in_[m]+bin) + r*(hn[m]+bhn);
            float e2 = __expf(2.f*pre);
            float nn = 1.f - 2.f/(e2+1.f);          // tanh
            float hold = sm.h[n*32+d];
            float hnew = (1.f-z)*nn + z*hold;
            sm.h[n*32+d] = hnew;                     // wave-private rows: no barrier needed
            if (last){
              long long oi = obase + (long long)(n - nbase)*32 + d;
              if (isbf) ((__hip_bfloat16*)p.out)[oi] = __float2bfloat16(hnew);
              else      ((float*)p.out)[oi] = hnew;
            }
          }
        }
      };
      int cntA = (ng<3)?9:8;    // 35 = 3*9 + 8
      int cntM = (ng<2)?5:4;    // 18 = 2*5 + 2*4
      gru(sm.w[0], sm.w[1], sm.gb[0], sm.gb[1], 0,  cntA, (long long)b*(NA*HH));
      gru(sm.w[2], sm.w[3], sm.gb[2], sm.gb[3], NA, cntM, (long long)OUT_MEO_BASE + (long long)b*(NM*HH));
    }
    // no barrier needed at loop end: ph5's LDS touches (gx read, h rw) are
    // disjoint from ph0's (xin write), and the ph0-end barrier orders the rest.
  }
}

extern "C" void kernel_launch(void* const* d_in, const int* in_sizes, int n_in,
                              void* d_out, int out_size, void* d_ws, size_t ws_size,
                              hipStream_t stream){
  (void)in_sizes; (void)n_in; (void)d_ws; (void)ws_size; (void)out_size;
  Params p;
  p.X_aqi = d_in[0];
  p.X_meo = d_in[1];
  p.ctx   = d_in[2];
  p.adj   = d_in[3];
  p.adjn  = d_in[4];
  p.emb0 = d_in[5];  p.emb1 = d_in[6];
  p.emb2 = d_in[7];  p.emb3 = d_in[8];
  p.emb4 = d_in[9];  p.emb5 = d_in[10];
  p.emb6 = d_in[11]; p.emb7 = d_in[12];
  p.emb8 = d_in[13];
  p.Wxa = d_in[14]; p.Wxm = d_in[15];
  p.Wua = d_in[16]; p.Wum = d_in[17];
  p.a0 = d_in[18]; p.a1 = d_in[19];
  p.a2 = d_in[20]; p.a3 = d_in[21];
  p.wih_a = d_in[22]; p.whh_a = d_in[23];
  p.bih_a = d_in[24]; p.bhh_a = d_in[25];
  p.wih_m = d_in[26]; p.whh_m = d_in[27];
  p.bih_m = d_in[28]; p.bhh_m = d_in[29];
  p.Xae = (const int*)d_in[30];
  p.Xme = (const int*)d_in[31];
  p.out = d_out;
  hipLaunchKernelGGL(chgat_gru_kernel, dim3(1024), dim3(256), 0, stream, p);
}